// Round 7
// baseline (153.355 us; speedup 1.0000x reference)
//
#include <hip/hip_runtime.h>
#include <math.h>

// CenterNetDecode fused: heat [8,80,192,192] f32, box [8,4,192,192] f32
// outputs (flat concat): boxes [B,H,W,4], mask [B,H,W], scores [B,H,W], center [B,H,W,2]
//
// Round-7 structure: register-free async channel pipeline.
// - REGISTER RULE (rounds 2-4): VGPR cap is 128; register double-buffering
//   spills catastrophically. So the double buffer lives in LDS, filled by
//   __builtin_amdgcn_global_load_lds (HBM->LDS DMA, zero VGPRs).
// - SS=2: strip+halo slab = 4 contiguous rows x 768 B = 3072 B = exactly
//   3 x (64 lanes x 16 B) DMA ops -> satisfies the wave-uniform-base+lane*16
//   LDS-dest constraint with a linear slab.
// - Per wave, per channel k: issue k+1's 3 DMAs into buf (k+1)&1, then
//   s_waitcnt vmcnt(3) (slab k ready, k+1 stays IN FLIGHT during compute —
//   never drain to 0 in the loop: T3/T4 counted-vmcnt pattern, per-wave,
//   no barriers). Rounds 5/6 showed the drain-then-compute pattern leaves
//   VMEM idle ~40% of the time and TLP alone doesn't fix it.
// - Edge strips: clamp slab base + per-row replicate mapping (max-equivalent
//   to -inf padding for a 3x3 window max).
// - LDS 48 KB (2 buf x 8 waves x 3 KB), reused for the cross-wave reduce
//   after the channel loop. 96 strips x 8 batches = 768 blocks = 3/CU
//   (LDS-limited), 24 waves/CU. batch->XCD swizzle kept (halo rows = L2
//   hits; verified by SS 6->3 being flat despite 2x logical halo reads).

#define BB 8
#define CC 80
#define HH 192
#define WW 192
#define SS 2                 // rows per block strip  (HH/SS = 96 strips)
#define NPIX (SS*WW)         // 384 pixels per block
#define NBPIX (BB*HH*WW)     // 294912
#define NT 512
#define NW (NT/64)           // 8 waves
#define CPW (CC/NW)          // 10 channels per wave
#define SLABROWS (SS+2)      // 4
#define SLABF (SLABROWS*WW)  // 768 floats = 3072 B per slab
#define LDSF (2*NW*SLABF)    // 12288 floats = 48 KB

typedef __attribute__((address_space(3))) unsigned int       lds_uint;
typedef __attribute__((address_space(1))) const unsigned int glb_uint;

__global__ __launch_bounds__(NT) void fused_kernel(const float* __restrict__ heat,
                                                   const float* __restrict__ box,
                                                   float* __restrict__ out) {
    const int tid  = threadIdx.x;
    const int lane = tid & 63;
    const int wv   = tid >> 6;        // wave 0..7
    const int bid  = blockIdx.x;      // 0..767 linear
    const int b    = bid & 7;         // XCD = bid % 8 == batch
    const int yt   = bid >> 3;        // 0..95 strip
    const int y0   = yt * SS;
    const bool lok = lane < 48;
    const int  col0 = lane * 4;

    __shared__ float smem[LDSF];      // slabs, later reused as red[]

    float4 sc[SS];
#pragma unroll
    for (int i = 0; i < SS; ++i) sc[i] = make_float4(0.f, 0.f, 0.f, 0.f);

    const int cbase   = wv * CPW;
    const float NI    = -INFINITY;
    // clamped slab base row (replicate padding at image top/bottom)
    const int baserow = min(max(y0 - 1, 0), HH - SLABROWS);
    int ridx[SLABROWS];               // logical halo row r -> slab row index
#pragma unroll
    for (int r = 0; r < SLABROWS; ++r)
        ridx[r] = min(max(y0 - 1 + r, baserow), baserow + SLABROWS - 1) - baserow;

    // issue one channel's slab (3 x 1024 B DMA) into LDS buffer BUF
#define ISSUE_SLAB(BUF, CH) {                                                  \
        const float* gsrc = heat + ((size_t)(b * CC + (CH)) * HH + baserow) * WW; \
        float* ldst = smem + (BUF) * (NW * SLABF) + wv * SLABF;                \
        _Pragma("unroll")                                                      \
        for (int ii = 0; ii < 3; ++ii) {                                       \
            __builtin_amdgcn_global_load_lds(                                  \
                (glb_uint*)(gsrc + ii * 256 + lane * 4),                       \
                (lds_uint*)(ldst + ii * 256), 16, 0, 0);                       \
        } }

    ISSUE_SLAB(0, cbase);                    // prologue: channel 0 in flight
#pragma unroll
    for (int k = 0; k < CPW; ++k) {
        if (k + 1 < CPW) {
            ISSUE_SLAB((k + 1) & 1, cbase + k + 1);
            asm volatile("s_waitcnt vmcnt(3)" ::: "memory");  // k ready, k+1 in flight
        } else {
            asm volatile("s_waitcnt vmcnt(0)" ::: "memory");  // last slab
        }
        const float* sk = smem + (k & 1) * (NW * SLABF) + wv * SLABF;
        float4 v[SLABROWS];
#pragma unroll
        for (int r = 0; r < SLABROWS; ++r)
            v[r] = lok ? *reinterpret_cast<const float4*>(sk + ridx[r] * WW + col0)
                       : make_float4(NI, NI, NI, NI);
#pragma unroll
        for (int i = 0; i < SS; ++i) {
            const float4 a = v[i], m = v[i + 1], d = v[i + 2];
            float4 vm;
            vm.x = fmaxf(fmaxf(a.x, m.x), d.x);
            vm.y = fmaxf(fmaxf(a.y, m.y), d.y);
            vm.z = fmaxf(fmaxf(a.z, m.z), d.z);
            vm.w = fmaxf(fmaxf(a.w, m.w), d.w);

            float L = __shfl_up(vm.w, 1);    // left neighbor's col (4l-1)
            float R = __shfl_down(vm.x, 1);  // right neighbor's col (4l+4)
            if (lane == 0)  L = NI;          // image left edge
            if (lane >= 47) R = NI;          // image right edge / inactive

            float4 hm;
            hm.x = fmaxf(fmaxf(L,    vm.x), vm.y);
            hm.y = fmaxf(fmaxf(vm.x, vm.y), vm.z);
            hm.z = fmaxf(fmaxf(vm.y, vm.z), vm.w);
            hm.w = fmaxf(fmaxf(vm.z, vm.w), R);

            sc[i].x = fmaxf(sc[i].x, (m.x == hm.x) ? m.x : 0.0f);
            sc[i].y = fmaxf(sc[i].y, (m.y == hm.y) ? m.y : 0.0f);
            sc[i].z = fmaxf(sc[i].z, (m.z == hm.z) ? m.z : 0.0f);
            sc[i].w = fmaxf(sc[i].w, (m.w == hm.w) ? m.w : 0.0f);
        }
    }

    // ---- decode prefetch: issue box loads BEFORE the barrier (latency hides
    //      under barrier + LDS reduce). Strip is linear: pix = pixbase + idx.
    const int    pixbase = (b * HH + y0) * WW;
    const float* bp0     = box + (size_t)b * 4 * HH * WW + (size_t)y0 * WW;
    const bool   dok     = tid < NPIX;
    float pdx = 0.f, pdy = 0.f, pbw = 0.f, pbh = 0.f;
    if (dok) {
        pdx = bp0[tid];
        pdy = bp0[tid + (size_t)HH * WW];
        pbw = bp0[tid + (size_t)2 * HH * WW];
        pbh = bp0[tid + (size_t)3 * HH * WW];
    }

    __syncthreads();                  // all waves done reading slabs
    // reuse smem as red[NW][SS][WW] (12 KB of the 48)
    if (lok) {
#pragma unroll
        for (int i = 0; i < SS; ++i)
            *reinterpret_cast<float4*>(smem + wv * NPIX + i * WW + col0) = sc[i];
    }
    __syncthreads();

    float* boxes  = out;
    float* maskp  = out + (size_t)4 * NBPIX;
    float* scorep = out + (size_t)5 * NBPIX;
    float* ctr    = out + (size_t)6 * NBPIX;

    if (dok) {
        const int idx = tid;
        const int row = idx / WW;
        const int x   = idx - row * WW;
        const int y   = y0 + row;

        float s = smem[idx];
#pragma unroll
        for (int w = 1; w < NW; ++w) s = fmaxf(s, smem[w * NPIX + idx]);
        const bool m = s > 0.7f;

        const float cx = ((float)x + pdx) * 4.0f;
        const float cy = ((float)y + pdy) * 4.0f;
        const float w4 = pbw * 4.0f;
        const float h4 = pbh * 4.0f;
        const float lim = 768.0f;
        const float x1 = fminf(fmaxf(cx - w4 * 0.5f, 0.0f), lim);
        const float y1 = fminf(fmaxf(cy - h4 * 0.5f, 0.0f), lim);
        const float x2 = fminf(fmaxf(cx + w4 * 0.5f, 0.0f), lim);
        const float y2 = fminf(fmaxf(cy + h4 * 0.5f, 0.0f), lim);

        const int pix = pixbase + idx;

        float4 bo;
        bo.x = m ? x1 : 0.0f;
        bo.y = m ? y1 : 0.0f;
        bo.z = m ? (x2 - x1) : 0.0f;
        bo.w = m ? (y2 - y1) : 0.0f;
        reinterpret_cast<float4*>(boxes)[pix] = bo;

        maskp[pix]  = m ? 1.0f : 0.0f;
        scorep[pix] = m ? s : 0.0f;

        float2 cc;
        cc.x = m ? cx : 0.0f;
        cc.y = m ? cy : 0.0f;
        reinterpret_cast<float2*>(ctr)[pix] = cc;
    }
}

extern "C" void kernel_launch(void* const* d_in, const int* in_sizes, int n_in,
                              void* d_out, int out_size, void* d_ws, size_t ws_size,
                              hipStream_t stream) {
    const float* heat = (const float*)d_in[0];
    const float* box  = (const float*)d_in[1];
    float* out = (float*)d_out;

    fused_kernel<<<dim3((HH / SS) * BB), NT, 0, stream>>>(heat, box, out);
}